// Round 1
// baseline (1351.614 us; speedup 1.0000x reference)
//
#include <hip/hip_runtime.h>
#include <math.h>

// minGRU: out = (scan(h_t = (1-z)h + z*g(hidden))) @ W_out^T
// Shapes: x[4,4096,1024] fp32, W_hg[2048,1024], W_out[1024,1024], out[4,4096,1024]

constexpr int Bsz  = 4;
constexpr int S    = 4096;
constexpr int Din  = 1024;
constexpr int Dh   = 1024;   // d_inner
constexpr int Dout = 1024;
constexpr int M    = Bsz * S;   // 16384

constexpr int NCH = 64;         // scan chunks along S
constexpr int CL  = S / NCH;    // 64 steps per chunk

__device__ __forceinline__ float sigf(float x) {
    return 1.0f / (1.0f + expf(-x));
}

// Dual-column-tile fp32 GEMM.
// A: [M x K] row-major. W: [* x K] row-major (so dot over contiguous K).
// Block computes 64 rows x 64 cols for TWO weight-row groups:
//   group0 = rows (bn0 + j), group1 = rows (off1 + bn0 + j).
// MODE 0: epilogue computes c = sigmoid(-gate), v = sigmoid(gate)*g(hidden)
//         (group0 = hidden, group1 = gate, off1 = 1024), writes to out0/out1.
// MODE 1: plain store: group0 -> out0 cols bn0.., group1 -> cols bn0+off1.
template<int MODE>
__global__ __launch_bounds__(256) void gemm_dual(
    const float* __restrict__ A, const float* __restrict__ W,
    float* __restrict__ out0, float* __restrict__ out1,
    int K, int off1)
{
    __shared__ float As[16][64];
    __shared__ float B0[16][64];
    __shared__ float B1[16][64];

    const int bn0 = blockIdx.x * 64;
    const int bm0 = blockIdx.y * 64;
    const int t   = threadIdx.x;
    const int tx  = t & 15;        // col group (x4)
    const int ty  = t >> 4;        // row group (x4)
    const int lrow = t >> 2;       // staging: row 0..63
    const int lk   = (t & 3) << 2; // staging: k 0,4,8,12

    const float* pA  = A + (size_t)(bm0 + lrow) * K + lk;
    const float* pW0 = W + (size_t)(bn0 + lrow) * K + lk;
    const float* pW1 = W + (size_t)(off1 + bn0 + lrow) * K + lk;

    float acc0[4][4] = {};
    float acc1[4][4] = {};

    for (int kb = 0; kb < K; kb += 16) {
        const float4 a  = *(const float4*)(pA  + kb);
        const float4 w0 = *(const float4*)(pW0 + kb);
        const float4 w1 = *(const float4*)(pW1 + kb);
        __syncthreads();
        As[lk+0][lrow] = a.x;  As[lk+1][lrow] = a.y;
        As[lk+2][lrow] = a.z;  As[lk+3][lrow] = a.w;
        B0[lk+0][lrow] = w0.x; B0[lk+1][lrow] = w0.y;
        B0[lk+2][lrow] = w0.z; B0[lk+3][lrow] = w0.w;
        B1[lk+0][lrow] = w1.x; B1[lk+1][lrow] = w1.y;
        B1[lk+2][lrow] = w1.z; B1[lk+3][lrow] = w1.w;
        __syncthreads();
        #pragma unroll
        for (int k = 0; k < 16; ++k) {
            const float4 ra4 = *(const float4*)&As[k][ty << 2];
            const float4 r04 = *(const float4*)&B0[k][tx << 2];
            const float4 r14 = *(const float4*)&B1[k][tx << 2];
            const float ra[4] = {ra4.x, ra4.y, ra4.z, ra4.w};
            const float r0[4] = {r04.x, r04.y, r04.z, r04.w};
            const float r1[4] = {r14.x, r14.y, r14.z, r14.w};
            #pragma unroll
            for (int i = 0; i < 4; ++i) {
                #pragma unroll
                for (int j = 0; j < 4; ++j) {
                    acc0[i][j] = fmaf(ra[i], r0[j], acc0[i][j]);
                    acc1[i][j] = fmaf(ra[i], r1[j], acc1[i][j]);
                }
            }
        }
    }

    #pragma unroll
    for (int i = 0; i < 4; ++i) {
        const int row  = bm0 + (ty << 2) + i;
        const int col0 = bn0 + (tx << 2);
        if (MODE == 0) {
            float4 cq, vq;
            float* cp = (float*)&cq;
            float* vp = (float*)&vq;
            #pragma unroll
            for (int j = 0; j < 4; ++j) {
                const float hid  = acc0[i][j];
                const float gate = acc1[i][j];
                const float z = sigf(gate);
                const float c = sigf(-gate);            // 1 - z, no cancellation
                const float g = (hid >= 0.0f) ? (hid + 0.5f) : sigf(hid);
                cp[j] = c;
                vp[j] = z * g;
            }
            *(float4*)&out0[(size_t)row * Dh + col0] = cq;
            *(float4*)&out1[(size_t)row * Dh + col0] = vq;
        } else {
            float4 q0, q1;
            float* p0 = (float*)&q0;
            float* p1 = (float*)&q1;
            #pragma unroll
            for (int j = 0; j < 4; ++j) { p0[j] = acc0[i][j]; p1[j] = acc1[i][j]; }
            *(float4*)&out0[(size_t)row * Dout + col0]        = q0;
            *(float4*)&out0[(size_t)row * Dout + col0 + off1] = q1;
        }
    }
}

// Scan stage 1: per (b, chunk, d): A = prod c, hl = local recurrence from 0.
__global__ __launch_bounds__(256) void scan_stage1(
    const float* __restrict__ cbuf, const float* __restrict__ vbuf,
    float* __restrict__ Abuf, float* __restrict__ hlbuf)
{
    const int g     = blockIdx.x * 256 + threadIdx.x;
    const int d     = g & (Dh - 1);
    const int chunk = (g >> 10) & (NCH - 1);
    const int b     = g >> 16;   // / (1024*64)
    const size_t base = ((size_t)(b * S + chunk * CL)) * Dh + d;
    float h = 0.0f, Aacc = 1.0f;
    #pragma unroll 4
    for (int i = 0; i < CL; ++i) {
        const float c = cbuf[base + (size_t)i * Dh];
        const float v = vbuf[base + (size_t)i * Dh];
        h = fmaf(c, h, v);
        Aacc *= c;
    }
    const size_t o = (size_t)(b * NCH + chunk) * Dh + d;
    Abuf[o]  = Aacc;
    hlbuf[o] = h;
}

// Scan stage 2: exclusive prefix across chunks per channel.
__global__ __launch_bounds__(256) void scan_stage2(
    const float* __restrict__ Abuf, const float* __restrict__ hlbuf,
    float* __restrict__ Hs)
{
    const int g = blockIdx.x * 256 + threadIdx.x;  // 0..B*Dh-1
    const int d = g & (Dh - 1);
    const int b = g >> 10;
    float h = 0.0f;
    for (int ch = 0; ch < NCH; ++ch) {
        const size_t o = (size_t)(b * NCH + ch) * Dh + d;
        Hs[o] = h;                       // h entering this chunk
        h = fmaf(Abuf[o], h, hlbuf[o]);
    }
}

// Scan stage 3: replay within chunk from Hs; write h in-place over vbuf.
__global__ __launch_bounds__(256) void scan_stage3(
    const float* __restrict__ cbuf, float* __restrict__ vbuf,
    const float* __restrict__ Hs)
{
    const int g     = blockIdx.x * 256 + threadIdx.x;
    const int d     = g & (Dh - 1);
    const int chunk = (g >> 10) & (NCH - 1);
    const int b     = g >> 16;
    const size_t base = ((size_t)(b * S + chunk * CL)) * Dh + d;
    float h = Hs[(size_t)(b * NCH + chunk) * Dh + d];
    #pragma unroll 4
    for (int i = 0; i < CL; ++i) {
        const size_t idx = base + (size_t)i * Dh;
        h = fmaf(cbuf[idx], h, vbuf[idx]);
        vbuf[idx] = h;
    }
}

extern "C" void kernel_launch(void* const* d_in, const int* in_sizes, int n_in,
                              void* d_out, int out_size, void* d_ws, size_t ws_size,
                              hipStream_t stream)
{
    (void)in_sizes; (void)n_in; (void)out_size; (void)ws_size;
    const float* x    = (const float*)d_in[0];
    const float* Whg  = (const float*)d_in[1];
    const float* Wout = (const float*)d_in[2];
    float* out = (float*)d_out;

    float* cbuf  = (float*)d_ws;                        // [M, Dh]  67.1 MB
    float* vbuf  = cbuf + (size_t)M * Dh;               // [M, Dh]  67.1 MB (v then h)
    float* Abuf  = vbuf + (size_t)M * Dh;               // [B, NCH, Dh] 1 MB
    float* hlbuf = Abuf + (size_t)Bsz * NCH * Dh;       // [B, NCH, Dh] 1 MB
    float* Hsbuf = hlbuf + (size_t)Bsz * NCH * Dh;      // [B, NCH, Dh] 1 MB

    const dim3 blk(256);

    // GEMM1 + fused gates: hidden/gate cols paired (off1 = Dh into W_hg rows)
    gemm_dual<0><<<dim3(Dh / 64, M / 64), blk, 0, stream>>>(
        x, Whg, cbuf, vbuf, Din, Dh);

    scan_stage1<<<dim3(Bsz * NCH * Dh / 256), blk, 0, stream>>>(cbuf, vbuf, Abuf, hlbuf);
    scan_stage2<<<dim3(Bsz * Dh / 256), blk, 0, stream>>>(Abuf, hlbuf, Hsbuf);
    scan_stage3<<<dim3(Bsz * NCH * Dh / 256), blk, 0, stream>>>(cbuf, vbuf, Hsbuf);

    // GEMM2: out = h @ W_out^T ; dual halves (off1 = Dout/2)
    gemm_dual<1><<<dim3(Dout / 128, M / 64), blk, 0, stream>>>(
        vbuf, Wout, out, nullptr, Dh, Dout / 2);
}

// Round 2
// 256.071 us; speedup vs baseline: 5.2783x; 5.2783x over previous
//
#include <hip/hip_runtime.h>
#include <math.h>

// minGRU: hg = x@Whg^T (bf16 MFMA) -> gates+scan (fp32) -> out = h@Wout^T (bf16 MFMA)
// x[4,4096,1024] f32, W_hg[2048,1024], W_out[1024,1024], out[4,4096,1024] f32

typedef unsigned short ushort_t;
typedef __attribute__((ext_vector_type(4))) float f32x4;
typedef __attribute__((ext_vector_type(8))) __bf16 bf16x8;
typedef __attribute__((ext_vector_type(8))) unsigned short u16x8;

constexpr int Bsz  = 4;
constexpr int S    = 4096;
constexpr int Din  = 1024;
constexpr int Dh   = 1024;
constexpr int M    = Bsz * S;      // 16384
constexpr int NCH  = 64;           // scan chunks along S
constexpr int CL   = S / NCH;      // 64

__device__ __forceinline__ unsigned short f2bf(float f) {
    unsigned int u = __float_as_uint(f);
    unsigned int r = (u + 0x7fffu + ((u >> 16) & 1u)) >> 16;   // RTN-even
    return (unsigned short)r;
}
__device__ __forceinline__ float bf2f(unsigned short u) {
    return __uint_as_float(((unsigned int)u) << 16);
}
__device__ __forceinline__ float sigf(float x) {
    x = fminf(fmaxf(x, -30.f), 30.f);
    return 1.0f / (1.0f + __expf(-x));
}
__device__ __forceinline__ void gld_lds16(const ushort_t* g, ushort_t* l) {
    __builtin_amdgcn_global_load_lds(
        (const __attribute__((address_space(1))) void*)g,
        (__attribute__((address_space(3))) void*)l, 16, 0, 0);
}

__global__ __launch_bounds__(256) void cvt_bf16(
    const float* __restrict__ in, ushort_t* __restrict__ out, int n8)
{
    const int i = blockIdx.x * 256 + threadIdx.x;
    if (i >= n8) return;
    const float4 a = ((const float4*)in)[i * 2];
    const float4 b = ((const float4*)in)[i * 2 + 1];
    u16x8 o;
    o[0] = f2bf(a.x); o[1] = f2bf(a.y); o[2] = f2bf(a.z); o[3] = f2bf(a.w);
    o[4] = f2bf(b.x); o[5] = f2bf(b.y); o[6] = f2bf(b.z); o[7] = f2bf(b.w);
    ((u16x8*)out)[i] = o;
}

// C[M x N] = A[M x K] * B[N x K]^T, bf16 in, f32 accum.
// 128x128 tile, BK=32, 4 waves (2x2 of 64x64), m97 structure.
// OUT_BF16: store C as bf16, else f32.
template<bool OUT_BF16>
__global__ __launch_bounds__(256) void gemm_bt(
    const ushort_t* __restrict__ A, int lda,
    const ushort_t* __restrict__ B, int ldb,
    void* __restrict__ Cout, int ldc, int K)
{
    __shared__ ushort_t lA[128 * 32];   // [row][k], 64 B rows
    __shared__ ushort_t lB[128 * 32];

    const int t   = threadIdx.x;
    const int w   = t >> 6;          // wave 0..3
    const int l   = t & 63;
    const int wr  = w >> 1;          // wave row (0..1) -> 64 rows
    const int wc  = w & 1;           // wave col (0..1) -> 64 cols
    const int bn0 = blockIdx.x * 128;
    const int bm0 = blockIdx.y * 128;

    // staging: wave w, inst q covers LDS rows w*32 + q*16 .. +16 (4 lanes/row)
    const int srow = w * 32 + (l >> 2);
    const int scol = (l & 3) * 8;
    const ushort_t* gA = A + (size_t)(bm0 + srow) * lda + scol;
    const ushort_t* gB = B + (size_t)(bn0 + srow) * ldb + scol;
    ushort_t* lAw = lA + w * 1024;   // elements (w*2048 bytes)
    ushort_t* lBw = lB + w * 1024;

    // fragment read offsets
    const int fr = l & 15;
    const int kg = l >> 4;
    const int aoff = (wr * 64 + fr) * 32 + kg * 8;
    const int boff = (wc * 64 + fr) * 32 + kg * 8;

    f32x4 acc[4][4];
    #pragma unroll
    for (int i = 0; i < 4; ++i)
        #pragma unroll
        for (int j = 0; j < 4; ++j)
            acc[i][j] = (f32x4){0.f, 0.f, 0.f, 0.f};

    for (int kb = 0; kb < K; kb += 32) {
        gld_lds16(gA + kb,            lAw);
        gld_lds16(gA + kb + 16 * lda, lAw + 512);
        gld_lds16(gB + kb,            lBw);
        gld_lds16(gB + kb + 16 * ldb, lBw + 512);
        __syncthreads();   // drains vmcnt -> LDS writes visible
        bf16x8 af[4], bf[4];
        #pragma unroll
        for (int i = 0; i < 4; ++i)
            af[i] = *reinterpret_cast<const bf16x8*>(&lA[aoff + i * 512]);
        #pragma unroll
        for (int j = 0; j < 4; ++j)
            bf[j] = *reinterpret_cast<const bf16x8*>(&lB[boff + j * 512]);
        #pragma unroll
        for (int i = 0; i < 4; ++i)
            #pragma unroll
            for (int j = 0; j < 4; ++j)
                acc[i][j] = __builtin_amdgcn_mfma_f32_16x16x32_bf16(
                    af[i], bf[j], acc[i][j], 0, 0, 0);
        __syncthreads();   // LDS reuse next iter
    }

    // C/D layout (m89): col = lane&15, row = (lane>>4)*4 + reg
    #pragma unroll
    for (int i = 0; i < 4; ++i) {
        #pragma unroll
        for (int j = 0; j < 4; ++j) {
            const int col = bn0 + wc * 64 + j * 16 + fr;
            #pragma unroll
            for (int r = 0; r < 4; ++r) {
                const int row = bm0 + wr * 64 + i * 16 + kg * 4 + r;
                if (OUT_BF16)
                    ((ushort_t*)Cout)[(size_t)row * ldc + col] = f2bf(acc[i][j][r]);
                else
                    ((float*)Cout)[(size_t)row * ldc + col] = acc[i][j][r];
            }
        }
    }
}

// ---- scan over S in 3 stages; gates recomputed from bf16 hg on the fly ----

__global__ __launch_bounds__(256) void scan_stage1(
    const ushort_t* __restrict__ hg, float* __restrict__ Abuf,
    float* __restrict__ hlbuf)
{
    const int g     = blockIdx.x * 256 + threadIdx.x;
    const int d     = g & (Dh - 1);
    const int chunk = (g >> 10) & (NCH - 1);
    const int b     = g >> 16;
    const size_t rowbase = (size_t)(b * S + chunk * CL) * 2048;
    float h = 0.0f, Aacc = 1.0f;
    #pragma unroll 4
    for (int i = 0; i < CL; ++i) {
        const float hid  = bf2f(hg[rowbase + (size_t)i * 2048 + d]);
        const float gate = bf2f(hg[rowbase + (size_t)i * 2048 + 1024 + d]);
        const float z  = sigf(gate);
        const float c  = sigf(-gate);
        const float gv = (hid >= 0.0f) ? (hid + 0.5f) : sigf(hid);
        h = fmaf(c, h, z * gv);
        Aacc *= c;
    }
    const size_t o = (size_t)(b * NCH + chunk) * Dh + d;
    Abuf[o]  = Aacc;
    hlbuf[o] = h;
}

__global__ __launch_bounds__(256) void scan_stage2(
    const float* __restrict__ Abuf, const float* __restrict__ hlbuf,
    float* __restrict__ Hs)
{
    const int g = blockIdx.x * 256 + threadIdx.x;   // 0..B*Dh-1
    const int d = g & (Dh - 1);
    const int b = g >> 10;
    float h = 0.0f;
    for (int ch = 0; ch < NCH; ++ch) {
        const size_t o = (size_t)(b * NCH + ch) * Dh + d;
        Hs[o] = h;
        h = fmaf(Abuf[o], h, hlbuf[o]);
    }
}

// replay chunk from Hs; write h (bf16) in-place over the gate half of hg
__global__ __launch_bounds__(256) void scan_stage3(
    ushort_t* __restrict__ hg, const float* __restrict__ Hs)
{
    const int g     = blockIdx.x * 256 + threadIdx.x;
    const int d     = g & (Dh - 1);
    const int chunk = (g >> 10) & (NCH - 1);
    const int b     = g >> 16;
    const size_t rowbase = (size_t)(b * S + chunk * CL) * 2048;
    float h = Hs[(size_t)(b * NCH + chunk) * Dh + d];
    #pragma unroll 4
    for (int i = 0; i < CL; ++i) {
        const size_t ro = rowbase + (size_t)i * 2048;
        const float hid  = bf2f(hg[ro + d]);
        const float gate = bf2f(hg[ro + 1024 + d]);
        const float z  = sigf(gate);
        const float c  = sigf(-gate);
        const float gv = (hid >= 0.0f) ? (hid + 0.5f) : sigf(hid);
        h = fmaf(c, h, z * gv);
        hg[ro + 1024 + d] = f2bf(h);   // this thread is the only reader of this slot
    }
}

extern "C" void kernel_launch(void* const* d_in, const int* in_sizes, int n_in,
                              void* d_out, int out_size, void* d_ws, size_t ws_size,
                              hipStream_t stream)
{
    (void)in_sizes; (void)n_in; (void)out_size; (void)ws_size;
    const float* x    = (const float*)d_in[0];
    const float* Whg  = (const float*)d_in[1];
    const float* Wout = (const float*)d_in[2];
    float* out = (float*)d_out;

    ushort_t* hgbuf = (ushort_t*)d_ws;                  // [M][2048] bf16  67.1 MB
    ushort_t* xb    = hgbuf + (size_t)M * 2048;         // [M][1024] bf16  33.5 MB
    ushort_t* whgb  = xb + (size_t)M * 1024;            // [2048][1024]     4.2 MB
    ushort_t* woutb = whgb + (size_t)2048 * 1024;       // [1024][1024]     2.1 MB
    float*    Abuf  = (float*)(woutb + (size_t)1024 * 1024);
    float*    hlbuf = Abuf + (size_t)Bsz * NCH * Dh;    // 1 MB each
    float*    Hsbuf = hlbuf + (size_t)Bsz * NCH * Dh;

    const dim3 blk(256);

    cvt_bf16<<<dim3(M * Din / 8 / 256), blk, 0, stream>>>(x, xb, M * Din / 8);
    cvt_bf16<<<dim3(2048 * 1024 / 8 / 256), blk, 0, stream>>>(Whg, whgb, 2048 * 1024 / 8);
    cvt_bf16<<<dim3(1024 * 1024 / 8 / 256), blk, 0, stream>>>(Wout, woutb, 1024 * 1024 / 8);

    // GEMM1: hg[M][2048] = x @ Whg^T  (bf16 out)
    gemm_bt<true><<<dim3(2048 / 128, M / 128), blk, 0, stream>>>(
        xb, Din, whgb, Din, hgbuf, 2048, Din);

    scan_stage1<<<dim3(Bsz * NCH * Dh / 256), blk, 0, stream>>>(hgbuf, Abuf, hlbuf);
    scan_stage2<<<dim3(Bsz * Dh / 256), blk, 0, stream>>>(Abuf, hlbuf, Hsbuf);
    scan_stage3<<<dim3(Bsz * NCH * Dh / 256), blk, 0, stream>>>(hgbuf, Hsbuf);

    // GEMM2: out[M][1024] = h @ Wout^T  (h = gate half of hg, lda 2048; f32 out)
    gemm_bt<false><<<dim3(1024 / 128, M / 128), blk, 0, stream>>>(
        hgbuf + 1024, 2048, woutb, Din, out, 1024, Dh);
}

// Round 3
// 215.476 us; speedup vs baseline: 6.2727x; 1.1884x over previous
//
#include <hip/hip_runtime.h>
#include <math.h>

// minGRU: hg = x@Whg^T (bf16 MFMA, 256^2 pipelined) -> gates+scan (fp32)
//         -> out = h@Wout^T (bf16 MFMA)
// x[4,4096,1024] f32, W_hg[2048,1024], W_out[1024,1024], out[4,4096,1024] f32

typedef unsigned short ushort_t;
typedef __attribute__((ext_vector_type(4))) float f32x4;
typedef __attribute__((ext_vector_type(8))) __bf16 bf16x8;
typedef __attribute__((ext_vector_type(8))) unsigned short u16x8;

constexpr int Bsz  = 4;
constexpr int S    = 4096;
constexpr int Din  = 1024;
constexpr int Dh   = 1024;
constexpr int M    = Bsz * S;      // 16384
constexpr int NCH  = 64;           // scan chunks along S
constexpr int CL   = S / NCH;      // 64

__device__ __forceinline__ unsigned short f2bf(float f) {
    unsigned int u = __float_as_uint(f);
    unsigned int r = (u + 0x7fffu + ((u >> 16) & 1u)) >> 16;   // RTN-even
    return (unsigned short)r;
}
__device__ __forceinline__ float bf2f(unsigned short u) {
    return __uint_as_float(((unsigned int)u) << 16);
}
__device__ __forceinline__ float sigf(float x) {
    x = fminf(fmaxf(x, -30.f), 30.f);
    return 1.0f / (1.0f + __expf(-x));
}
__device__ __forceinline__ void gld_lds16(const ushort_t* g, ushort_t* l) {
    __builtin_amdgcn_global_load_lds(
        (const __attribute__((address_space(1))) void*)g,
        (__attribute__((address_space(3))) void*)l, 16, 0, 0);
}

__global__ __launch_bounds__(256) void cvt_bf16(
    const float* __restrict__ in, ushort_t* __restrict__ out, int n8)
{
    const int i = blockIdx.x * 256 + threadIdx.x;
    if (i >= n8) return;
    const float4 a = ((const float4*)in)[i * 2];
    const float4 b = ((const float4*)in)[i * 2 + 1];
    u16x8 o;
    o[0] = f2bf(a.x); o[1] = f2bf(a.y); o[2] = f2bf(a.z); o[3] = f2bf(a.w);
    o[4] = f2bf(b.x); o[5] = f2bf(b.y); o[6] = f2bf(b.z); o[7] = f2bf(b.w);
    ((u16x8*)out)[i] = o;
}

// C[M x N] = A[M x K] * B[N x K]^T, bf16 in, f32 accum.
// 256x256 tile, 8 waves (2Mx4N), phases of K=32, 4-slot LDS ring,
// st_16x32 swizzle, counted vmcnt, raw barriers, setprio.
template<bool OUT_BF16>
__global__ __launch_bounds__(512, 2) void gemm256(
    const ushort_t* __restrict__ A, int lda,
    const ushort_t* __restrict__ B, int ldb,
    void* __restrict__ Cout, int ldc, int K, int nbx_log2)
{
    // slot = [256 rows][32 cols] bf16, subtiled [16][32] (1024B subtiles),
    // swizzle: byte ^= ((row&8)>>3)<<5 within subtile.
    __shared__ ushort_t lds[4][2][8192];   // [slot][A=0/B=1][256*32] = 128 KiB

    const int P = K >> 5;                  // phases (K=1024 -> 32)

    // ---- XCD-bijective block swizzle (gridDim.x % 8 == 0) ----
    const int nwg = gridDim.x;
    const int cpx = nwg >> 3;
    const int b   = blockIdx.x;
    const int swz = (b & 7) * cpx + (b >> 3);
    const int bx  = swz & ((1 << nbx_log2) - 1);
    const int by  = swz >> nbx_log2;
    const int bm0 = by * 256;
    const int bn0 = bx * 256;

    const int t  = threadIdx.x;
    const int w  = t >> 6;           // wave 0..7
    const int l  = t & 63;
    const int wr = w >> 2;           // 0..1 -> 128 rows
    const int wc = w & 3;            // 0..3 -> 64 cols

    // fragment read offsets (elements), swizzle folded in
    const int fr = l & 15;
    const int kg = l >> 4;
    const int qp = kg ^ (((fr >> 3) & 1) << 1);
    const int a_base = wr * 4096 + fr * 32 + qp * 8;   // + mf*512
    const int b_base = wc * 2048 + fr * 32 + qp * 8;   // + nf*512

    // staging: lane -> (subtile row, quarter); pre-swizzled global source
    const int rs = l >> 2;
    const int lq = (l & 3) ^ (((rs >> 3) & 1) << 1);
    const ushort_t* gA0 = A + (size_t)(bm0 + w * 16 + rs) * lda + lq * 8;
    const ushort_t* gA1 = gA0 + (size_t)128 * lda;
    const ushort_t* gB0 = B + (size_t)(bn0 + w * 16 + rs) * ldb + lq * 8;
    const ushort_t* gB1 = gB0 + (size_t)128 * ldb;

    f32x4 acc[8][4];
    #pragma unroll
    for (int i = 0; i < 8; ++i)
        #pragma unroll
        for (int j = 0; j < 4; ++j)
            acc[i][j] = (f32x4){0.f, 0.f, 0.f, 0.f};

    auto stage = [&](int p) {   // 4 global_load_lds for phase p's slot
        const int s2 = p & 3;
        const int ko = p * 32;
        gld_lds16(gA0 + ko, &lds[s2][0][w * 512]);
        gld_lds16(gA1 + ko, &lds[s2][0][w * 512 + 4096]);
        gld_lds16(gB0 + ko, &lds[s2][1][w * 512]);
        gld_lds16(gB1 + ko, &lds[s2][1][w * 512 + 4096]);
    };

    auto phase_body = [&](int p, bool do_stage) {
        __builtin_amdgcn_s_barrier();
        __builtin_amdgcn_sched_barrier(0);
        const int s = p & 3;
        const ushort_t* la = &lds[s][0][0];
        const ushort_t* lb = &lds[s][1][0];
        bf16x8 af[8], bfr[4];
        #pragma unroll
        for (int i = 0; i < 8; ++i)
            af[i] = *(const bf16x8*)&la[a_base + i * 512];
        #pragma unroll
        for (int j = 0; j < 4; ++j)
            bfr[j] = *(const bf16x8*)&lb[b_base + j * 512];
        if (do_stage) stage(p + 2);
        __builtin_amdgcn_sched_barrier(0);
        __builtin_amdgcn_s_setprio(1);
        #pragma unroll
        for (int i = 0; i < 8; ++i)
            #pragma unroll
            for (int j = 0; j < 4; ++j)
                acc[i][j] = __builtin_amdgcn_mfma_f32_16x16x32_bf16(
                    af[i], bfr[j], acc[i][j], 0, 0, 0);
        __builtin_amdgcn_s_setprio(0);
        __builtin_amdgcn_sched_barrier(0);
    };

    // prologue: stage phases 0 and 1 (8 loads in flight)
    stage(0);
    stage(1);

    for (int p = 0; p < P - 1; ++p) {
        // steady state: 8 outstanding (stage p, stage p+1); drain oldest 4
        asm volatile("s_waitcnt vmcnt(4)" ::: "memory");
        phase_body(p, p < P - 2);
    }
    asm volatile("s_waitcnt vmcnt(0)" ::: "memory");
    phase_body(P - 1, false);

    // C/D layout: col = lane&15, row = (lane>>4)*4 + reg
    #pragma unroll
    for (int i = 0; i < 8; ++i) {
        #pragma unroll
        for (int j = 0; j < 4; ++j) {
            const int col = bn0 + wc * 64 + j * 16 + fr;
            #pragma unroll
            for (int r = 0; r < 4; ++r) {
                const int row = bm0 + wr * 128 + i * 16 + kg * 4 + r;
                if (OUT_BF16)
                    ((ushort_t*)Cout)[(size_t)row * ldc + col] = f2bf(acc[i][j][r]);
                else
                    ((float*)Cout)[(size_t)row * ldc + col] = acc[i][j][r];
            }
        }
    }
}

// ---- scan over S in 3 stages; gates recomputed from bf16 hg on the fly ----

__global__ __launch_bounds__(256) void scan_stage1(
    const ushort_t* __restrict__ hg, float* __restrict__ Abuf,
    float* __restrict__ hlbuf)
{
    const int g     = blockIdx.x * 256 + threadIdx.x;
    const int d     = g & (Dh - 1);
    const int chunk = (g >> 10) & (NCH - 1);
    const int b     = g >> 16;
    const size_t rowbase = (size_t)(b * S + chunk * CL) * 2048;
    float h = 0.0f, Aacc = 1.0f;
    #pragma unroll 4
    for (int i = 0; i < CL; ++i) {
        const float hid  = bf2f(hg[rowbase + (size_t)i * 2048 + d]);
        const float gate = bf2f(hg[rowbase + (size_t)i * 2048 + 1024 + d]);
        const float z  = sigf(gate);
        const float c  = sigf(-gate);
        const float gv = (hid >= 0.0f) ? (hid + 0.5f) : sigf(hid);
        h = fmaf(c, h, z * gv);
        Aacc *= c;
    }
    const size_t o = (size_t)(b * NCH + chunk) * Dh + d;
    Abuf[o]  = Aacc;
    hlbuf[o] = h;
}

__global__ __launch_bounds__(256) void scan_stage2(
    const float* __restrict__ Abuf, const float* __restrict__ hlbuf,
    float* __restrict__ Hs)
{
    const int g = blockIdx.x * 256 + threadIdx.x;   // 0..B*Dh-1
    const int d = g & (Dh - 1);
    const int b = g >> 10;
    float h = 0.0f;
    for (int ch = 0; ch < NCH; ++ch) {
        const size_t o = (size_t)(b * NCH + ch) * Dh + d;
        Hs[o] = h;
        h = fmaf(Abuf[o], h, hlbuf[o]);
    }
}

// replay chunk from Hs; write h (bf16) COMPACT into hout [M][1024]
__global__ __launch_bounds__(256) void scan_stage3(
    const ushort_t* __restrict__ hg, const float* __restrict__ Hs,
    ushort_t* __restrict__ hout)
{
    const int g     = blockIdx.x * 256 + threadIdx.x;
    const int d     = g & (Dh - 1);
    const int chunk = (g >> 10) & (NCH - 1);
    const int b     = g >> 16;
    const size_t rowbase = (size_t)(b * S + chunk * CL) * 2048;
    const size_t hbase   = (size_t)(b * S + chunk * CL) * 1024 + d;
    float h = Hs[(size_t)(b * NCH + chunk) * Dh + d];
    #pragma unroll 4
    for (int i = 0; i < CL; ++i) {
        const size_t ro = rowbase + (size_t)i * 2048;
        const float hid  = bf2f(hg[ro + d]);
        const float gate = bf2f(hg[ro + 1024 + d]);
        const float z  = sigf(gate);
        const float c  = sigf(-gate);
        const float gv = (hid >= 0.0f) ? (hid + 0.5f) : sigf(hid);
        h = fmaf(c, h, z * gv);
        hout[hbase + (size_t)i * 1024] = f2bf(h);
    }
}

extern "C" void kernel_launch(void* const* d_in, const int* in_sizes, int n_in,
                              void* d_out, int out_size, void* d_ws, size_t ws_size,
                              hipStream_t stream)
{
    (void)in_sizes; (void)n_in; (void)out_size; (void)ws_size;
    const float* x    = (const float*)d_in[0];
    const float* Whg  = (const float*)d_in[1];
    const float* Wout = (const float*)d_in[2];
    float* out = (float*)d_out;

    ushort_t* hgbuf = (ushort_t*)d_ws;                  // [M][2048] bf16  67.1 MB
    ushort_t* xb    = hgbuf + (size_t)M * 2048;         // [M][1024] bf16  33.5 MB (x, then h)
    ushort_t* whgb  = xb + (size_t)M * 1024;            // [2048][1024]     4.2 MB
    ushort_t* woutb = whgb + (size_t)2048 * 1024;       // [1024][1024]     2.1 MB
    float*    Abuf  = (float*)(woutb + (size_t)1024 * 1024);
    float*    hlbuf = Abuf + (size_t)Bsz * NCH * Dh;    // 1 MB each
    float*    Hsbuf = hlbuf + (size_t)Bsz * NCH * Dh;

    const dim3 blk(256);

    cvt_bf16<<<dim3(M * Din / 8 / 256), blk, 0, stream>>>(x, xb, M * Din / 8);
    cvt_bf16<<<dim3(2048 * 1024 / 8 / 256), blk, 0, stream>>>(Whg, whgb, 2048 * 1024 / 8);
    cvt_bf16<<<dim3(1024 * 1024 / 8 / 256), blk, 0, stream>>>(Wout, woutb, 1024 * 1024 / 8);

    // GEMM1: hg[M][2048] = x @ Whg^T  (bf16 out); grid 64x8 = 512
    gemm256<true><<<dim3(512), dim3(512), 0, stream>>>(
        xb, Din, whgb, Din, hgbuf, 2048, Din, 3);

    scan_stage1<<<dim3(Bsz * NCH * Dh / 256), blk, 0, stream>>>(hgbuf, Abuf, hlbuf);
    scan_stage2<<<dim3(Bsz * Dh / 256), blk, 0, stream>>>(Abuf, hlbuf, Hsbuf);
    scan_stage3<<<dim3(Bsz * NCH * Dh / 256), blk, 0, stream>>>(hgbuf, Hsbuf, xb);

    // GEMM2: out[M][1024] = h @ Wout^T  (f32 out); grid 64x4 = 256
    gemm256<false><<<dim3(256), dim3(512), 0, stream>>>(
        xb, Dh, woutb, Din, out, 1024, Dh, 2);
}

// Round 5
// 211.575 us; speedup vs baseline: 6.3883x; 1.0184x over previous
//
#include <hip/hip_runtime.h>
#include <math.h>

// minGRU: hg = x@Whg^T (bf16 MFMA, 256^2 4-phase/K-tile pipeline) -> gates+scan (fp32)
//         -> out = h@Wout^T (bf16 MFMA)
// x[4,4096,1024] f32, W_hg[2048,1024], W_out[1024,1024], out[4,4096,1024] f32

typedef unsigned short ushort_t;
typedef __attribute__((ext_vector_type(4))) float f32x4;
typedef __attribute__((ext_vector_type(8))) __bf16 bf16x8;
typedef __attribute__((ext_vector_type(8))) unsigned short u16x8;

constexpr int Bsz  = 4;
constexpr int S    = 4096;
constexpr int Din  = 1024;
constexpr int Dh   = 1024;
constexpr int M    = Bsz * S;      // 16384
constexpr int NCH  = 64;           // scan chunks along S
constexpr int CL   = S / NCH;      // 64

__device__ __forceinline__ unsigned short f2bf(float f) {
    unsigned int u = __float_as_uint(f);
    unsigned int r = (u + 0x7fffu + ((u >> 16) & 1u)) >> 16;   // RTN-even
    return (unsigned short)r;
}
__device__ __forceinline__ float bf2f(unsigned short u) {
    return __uint_as_float(((unsigned int)u) << 16);
}
__device__ __forceinline__ float sigf(float x) {
    x = fminf(fmaxf(x, -30.f), 30.f);
    return 1.0f / (1.0f + __expf(-x));
}
__device__ __forceinline__ void gld_lds16(const ushort_t* g, ushort_t* l) {
    __builtin_amdgcn_global_load_lds(
        (const __attribute__((address_space(1))) void*)g,
        (__attribute__((address_space(3))) void*)l, 16, 0, 0);
}

// one kernel converting all three f32 inputs to bf16
__global__ __launch_bounds__(256) void cvt_all(
    const float* __restrict__ x, const float* __restrict__ whg,
    const float* __restrict__ wout,
    ushort_t* __restrict__ xb, ushort_t* __restrict__ whgb,
    ushort_t* __restrict__ woutb)
{
    constexpr int NX = M * Din / 8;          // 2097152
    constexpr int NW = 2048 * 1024 / 8;      // 262144
    const int i = blockIdx.x * 256 + threadIdx.x;
    const float* src; ushort_t* dst; int k;
    if (i < NX)            { src = x;    dst = xb;    k = i; }
    else if (i < NX + NW)  { src = whg;  dst = whgb;  k = i - NX; }
    else                   { src = wout; dst = woutb; k = i - NX - NW; }
    const float4 a = ((const float4*)src)[(size_t)k * 2];
    const float4 b = ((const float4*)src)[(size_t)k * 2 + 1];
    u16x8 o;
    o[0] = f2bf(a.x); o[1] = f2bf(a.y); o[2] = f2bf(a.z); o[3] = f2bf(a.w);
    o[4] = f2bf(b.x); o[5] = f2bf(b.y); o[6] = f2bf(b.z); o[7] = f2bf(b.w);
    ((u16x8*)dst)[k] = o;
}

// C[M x N] = A[M x K] * B[N x K]^T, bf16 in, f32 accum.
// 256x256 tile, 8 waves (2Mx4N), K-tiles of 64, 4 phases/tile:
//   phase = {barrier; stage 1 region; vmcnt(8); ds_read frags; 16 MFMA}
// LDS: 2 bufs x (A 32KB + B 32KB) = 128 KiB.
// A buf quarters: q0=rows 0-63, q1=rows 128-191, q2=rows 64-127, q3=rows 192-255;
//   row-major 64x128B, read-swizzle colbyte ^= (row&7)<<4 (inverse applied at source).
// B buf: [ks][256 rows][64B], read-swizzle colbyte ^= ((row>>1)&3)<<4.
// Sync invariants (verified):
//   prologue vmcnt(6) drains tile0 before first barrier;
//   steady state: 8 in flight, vmcnt(8) drains exactly the stage from 4 phases ago;
//   every LDS read's data was drained by ALL waves' vmcnt >=1 barrier earlier;
//   last tile: vmcnt(0) before its first barrier (no stages left to force drains).
template<bool OUT_BF16>
__global__ __launch_bounds__(512, 2) void gemm256(
    const ushort_t* __restrict__ A, int lda,
    const ushort_t* __restrict__ B, int ldb,
    void* __restrict__ Cout, int ldc, int K, int nbx_log2)
{
    __shared__ ushort_t lds[2][2][16384];   // [buf][A/B][32KB]
    char* const ldsb = (char*)&lds[0][0][0];

    const int NT = K >> 6;                  // K-tiles (K=1024 -> 16)

    // XCD-bijective block swizzle (gridDim.x % 8 == 0)
    const int nwg = gridDim.x;
    const int cpx = nwg >> 3;
    const int bid = blockIdx.x;
    const int swz = (bid & 7) * cpx + (bid >> 3);
    const int bx  = swz & ((1 << nbx_log2) - 1);
    const int by  = swz >> nbx_log2;
    const int bm0 = by * 256;
    const int bn0 = bx * 256;

    const int t  = threadIdx.x;
    const int w  = t >> 6;           // wave 0..7
    const int l  = t & 63;
    const int wr = w >> 2;           // 0..1 -> 128 rows
    const int wc = w & 3;            // 0..3 -> 64 cols

    // ---- fragment read offsets (bytes) ----
    const int fr = l & 15;
    const int kg = l >> 4;
    const int a_row_byte = fr * 128;                       // + i*2048
    const int a_col0 = (kg * 16) ^ ((fr & 7) << 4);        // ks=0, swizzled
    const int a_col1 = a_col0 ^ 64;                        // ks=1
    const int b_row_byte = (wc * 64 + fr) * 64
                         + ((kg * 16) ^ (((fr >> 1) & 3) << 4));

    // ---- staging constants (pre-swizzled global source, linear LDS dest) ----
    // A: wave w inst n -> LDS quarter rows; source rows mapped so that
    //    quarters hold {0-63, 128-191, 64-127, 192-255}.
    const int rA      = w * 16 + (l >> 3);
    const int rowA0p  = ((rA     ) >> 6) * 128 + ((rA     ) & 63);
    const int rowA1p  = ((rA +  8) >> 6) * 128 + ((rA +  8) & 63);
    const int acolA   = (((l & 7) * 16) ^ (((l >> 3) & 7) << 4)) >> 1;  // elements
    const ushort_t* aS0 = A + (size_t)(bm0 + rowA0p) * lda + acolA;
    const ushort_t* aS1 = A + (size_t)(bm0 + rowA1p) * lda + acolA;
    const size_t aMh = (size_t)64 * lda;    // +64 source rows for mh=1
    // B: wave w covers rows w*32 .. w*32+31
    const int brA  = w * 32 + (l >> 2);
    const int bcol = ((l & 3) ^ ((l >> 3) & 3)) * 8;       // elements
    const ushort_t* bS0 = B + (size_t)(bn0 + brA) * ldb + bcol;
    const ushort_t* bS1 = bS0 + (size_t)16 * ldb;

    auto stageA = [&](int Tt, int mh) {
        char* db = ldsb + (size_t)(Tt & 1) * 65536 + mh * 16384 + w * 2048;
        const size_t go = (size_t)mh * aMh + Tt * 64;
        gld_lds16(aS0 + go, (ushort_t*)db);
        gld_lds16(aS1 + go, (ushort_t*)(db + 1024));
    };
    auto stageB = [&](int Tt, int ks) {
        char* db = ldsb + (size_t)(Tt & 1) * 65536 + 32768 + ks * 16384 + w * 2048;
        const int go = Tt * 64 + ks * 32;
        gld_lds16(bS0 + go, (ushort_t*)db);
        gld_lds16(bS1 + go, (ushort_t*)(db + 1024));
    };

    f32x4 acc[8][4];
    #pragma unroll
    for (int i = 0; i < 8; ++i)
        #pragma unroll
        for (int j = 0; j < 4; ++j)
            acc[i][j] = (f32x4){0.f, 0.f, 0.f, 0.f};

    bf16x8 bfr0[4], bfr1[4];   // B frags ks0/ks1, persist across mh phases

    // ---- prologue: tile0 fully + tile1 {Bk0, Bk1, Arh0} = 14 loads ----
    stageB(0, 0); stageB(0, 1); stageA(0, 0); stageA(0, 1);
    stageB(1, 0); stageB(1, 1); stageA(1, 0);
    asm volatile("s_waitcnt vmcnt(6)" ::: "memory");   // tile0 landed (per-wave)

    #pragma unroll 1
    for (int T = 0; T < NT; ++T) {
        if (T == NT - 1)
            asm volatile("s_waitcnt vmcnt(0)" ::: "memory");  // tail drain
        const char* abuf = ldsb + (size_t)(T & 1) * 65536;
        const char* bbuf = abuf + 32768;

        // ---- q0: (mh0, ks0); stage A-rh1(T+1) ----
        __builtin_amdgcn_s_barrier();
        __builtin_amdgcn_sched_barrier(0);
        if (T + 1 < NT) stageA(T + 1, 1);
        asm volatile("s_waitcnt vmcnt(8)" ::: "memory");
        __builtin_amdgcn_sched_barrier(0);
        {
            #pragma unroll
            for (int j = 0; j < 4; ++j)
                bfr0[j] = *(const bf16x8*)(bbuf + j * 1024 + b_row_byte);
            bf16x8 af[4];
            #pragma unroll
            for (int i = 0; i < 4; ++i)
                af[i] = *(const bf16x8*)(abuf + wr * 8192 + i * 2048 + a_row_byte + a_col0);
            __builtin_amdgcn_s_setprio(1);
            #pragma unroll
            for (int i = 0; i < 4; ++i)
                #pragma unroll
                for (int j = 0; j < 4; ++j)
                    acc[i][j] = __builtin_amdgcn_mfma_f32_16x16x32_bf16(
                        af[i], bfr0[j], acc[i][j], 0, 0, 0);
            __builtin_amdgcn_s_setprio(0);
            __builtin_amdgcn_sched_barrier(0);
        }

        // ---- q1: (mh0, ks1); stage B-k0(T+2) ----
        __builtin_amdgcn_s_barrier();
        __builtin_amdgcn_sched_barrier(0);
        if (T + 2 < NT) stageB(T + 2, 0);
        asm volatile("s_waitcnt vmcnt(8)" ::: "memory");
        __builtin_amdgcn_sched_barrier(0);
        {
            #pragma unroll
            for (int j = 0; j < 4; ++j)
                bfr1[j] = *(const bf16x8*)(bbuf + 16384 + j * 1024 + b_row_byte);
            bf16x8 af[4];
            #pragma unroll
            for (int i = 0; i < 4; ++i)
                af[i] = *(const bf16x8*)(abuf + wr * 8192 + i * 2048 + a_row_byte + a_col1);
            __builtin_amdgcn_s_setprio(1);
            #pragma unroll
            for (int i = 0; i < 4; ++i)
                #pragma unroll
                for (int j = 0; j < 4; ++j)
                    acc[i][j] = __builtin_amdgcn_mfma_f32_16x16x32_bf16(
                        af[i], bfr1[j], acc[i][j], 0, 0, 0);
            __builtin_amdgcn_s_setprio(0);
            __builtin_amdgcn_sched_barrier(0);
        }

        // ---- q2: (mh1, ks0); stage B-k1(T+2); reuse bfr0 ----
        __builtin_amdgcn_s_barrier();
        __builtin_amdgcn_sched_barrier(0);
        if (T + 2 < NT) stageB(T + 2, 1);
        asm volatile("s_waitcnt vmcnt(8)" ::: "memory");
        __builtin_amdgcn_sched_barrier(0);
        {
            bf16x8 af[4];
            #pragma unroll
            for (int i = 0; i < 4; ++i)
                af[i] = *(const bf16x8*)(abuf + 16384 + wr * 8192 + i * 2048 + a_row_byte + a_col0);
            __builtin_amdgcn_s_setprio(1);
            #pragma unroll
            for (int i = 0; i < 4; ++i)
                #pragma unroll
                for (int j = 0; j < 4; ++j)
                    acc[4 + i][j] = __builtin_amdgcn_mfma_f32_16x16x32_bf16(
                        af[i], bfr0[j], acc[4 + i][j], 0, 0, 0);
            __builtin_amdgcn_s_setprio(0);
            __builtin_amdgcn_sched_barrier(0);
        }

        // ---- q3: (mh1, ks1); stage A-rh0(T+2); reuse bfr1 ----
        __builtin_amdgcn_s_barrier();
        __builtin_amdgcn_sched_barrier(0);
        if (T + 2 < NT) stageA(T + 2, 0);
        asm volatile("s_waitcnt vmcnt(8)" ::: "memory");
        __builtin_amdgcn_sched_barrier(0);
        {
            bf16x8 af[4];
            #pragma unroll
            for (int i = 0; i < 4; ++i)
                af[i] = *(const bf16x8*)(abuf + 16384 + wr * 8192 + i * 2048 + a_row_byte + a_col1);
            __builtin_amdgcn_s_setprio(1);
            #pragma unroll
            for (int i = 0; i < 4; ++i)
                #pragma unroll
                for (int j = 0; j < 4; ++j)
                    acc[4 + i][j] = __builtin_amdgcn_mfma_f32_16x16x32_bf16(
                        af[i], bfr1[j], acc[4 + i][j], 0, 0, 0);
            __builtin_amdgcn_s_setprio(0);
            __builtin_amdgcn_sched_barrier(0);
        }
    }

    // C/D layout: col = lane&15, row = (lane>>4)*4 + reg
    #pragma unroll
    for (int i = 0; i < 8; ++i) {
        #pragma unroll
        for (int j = 0; j < 4; ++j) {
            const int col = bn0 + wc * 64 + j * 16 + fr;
            #pragma unroll
            for (int r = 0; r < 4; ++r) {
                const int row = bm0 + wr * 128 + i * 16 + kg * 4 + r;
                if (OUT_BF16)
                    ((ushort_t*)Cout)[(size_t)row * ldc + col] = f2bf(acc[i][j][r]);
                else
                    ((float*)Cout)[(size_t)row * ldc + col] = acc[i][j][r];
            }
        }
    }
}

// ---- scan over S in 3 stages; gates recomputed from bf16 hg on the fly ----

__global__ __launch_bounds__(256) void scan_stage1(
    const ushort_t* __restrict__ hg, float* __restrict__ Abuf,
    float* __restrict__ hlbuf)
{
    const int g     = blockIdx.x * 256 + threadIdx.x;
    const int d     = g & (Dh - 1);
    const int chunk = (g >> 10) & (NCH - 1);
    const int b     = g >> 16;
    const size_t rowbase = (size_t)(b * S + chunk * CL) * 2048;
    float h = 0.0f, Aacc = 1.0f;
    #pragma unroll 4
    for (int i = 0; i < CL; ++i) {
        const float hid  = bf2f(hg[rowbase + (size_t)i * 2048 + d]);
        const float gate = bf2f(hg[rowbase + (size_t)i * 2048 + 1024 + d]);
        const float z  = sigf(gate);
        const float c  = sigf(-gate);
        const float gv = (hid >= 0.0f) ? (hid + 0.5f) : sigf(hid);
        h = fmaf(c, h, z * gv);
        Aacc *= c;
    }
    const size_t o = (size_t)(b * NCH + chunk) * Dh + d;
    Abuf[o]  = Aacc;
    hlbuf[o] = h;
}

__global__ __launch_bounds__(256) void scan_stage2(
    const float* __restrict__ Abuf, const float* __restrict__ hlbuf,
    float* __restrict__ Hs)
{
    const int g = blockIdx.x * 256 + threadIdx.x;   // 0..B*Dh-1
    const int d = g & (Dh - 1);
    const int b = g >> 10;
    float h = 0.0f;
    for (int ch = 0; ch < NCH; ++ch) {
        const size_t o = (size_t)(b * NCH + ch) * Dh + d;
        Hs[o] = h;
        h = fmaf(Abuf[o], h, hlbuf[o]);
    }
}

// replay chunk from Hs; write h (bf16) COMPACT into hout [M][1024]
__global__ __launch_bounds__(256) void scan_stage3(
    const ushort_t* __restrict__ hg, const float* __restrict__ Hs,
    ushort_t* __restrict__ hout)
{
    const int g     = blockIdx.x * 256 + threadIdx.x;
    const int d     = g & (Dh - 1);
    const int chunk = (g >> 10) & (NCH - 1);
    const int b     = g >> 16;
    const size_t rowbase = (size_t)(b * S + chunk * CL) * 2048;
    const size_t hbase   = (size_t)(b * S + chunk * CL) * 1024 + d;
    float h = Hs[(size_t)(b * NCH + chunk) * Dh + d];
    #pragma unroll 4
    for (int i = 0; i < CL; ++i) {
        const size_t ro = rowbase + (size_t)i * 2048;
        const float hid  = bf2f(hg[ro + d]);
        const float gate = bf2f(hg[ro + 1024 + d]);
        const float z  = sigf(gate);
        const float c  = sigf(-gate);
        const float gv = (hid >= 0.0f) ? (hid + 0.5f) : sigf(hid);
        h = fmaf(c, h, z * gv);
        hout[hbase + (size_t)i * 1024] = f2bf(h);
    }
}

extern "C" void kernel_launch(void* const* d_in, const int* in_sizes, int n_in,
                              void* d_out, int out_size, void* d_ws, size_t ws_size,
                              hipStream_t stream)
{
    (void)in_sizes; (void)n_in; (void)out_size; (void)ws_size;
    const float* x    = (const float*)d_in[0];
    const float* Whg  = (const float*)d_in[1];
    const float* Wout = (const float*)d_in[2];
    float* out = (float*)d_out;

    ushort_t* hgbuf = (ushort_t*)d_ws;                  // [M][2048] bf16  67.1 MB
    ushort_t* xb    = hgbuf + (size_t)M * 2048;         // [M][1024] bf16  33.5 MB (x, then h)
    ushort_t* whgb  = xb + (size_t)M * 1024;            // [2048][1024]     4.2 MB
    ushort_t* woutb = whgb + (size_t)2048 * 1024;       // [1024][1024]     2.1 MB
    float*    Abuf  = (float*)(woutb + (size_t)1024 * 1024);
    float*    hlbuf = Abuf + (size_t)Bsz * NCH * Dh;    // 1 MB each
    float*    Hsbuf = hlbuf + (size_t)Bsz * NCH * Dh;

    const dim3 blk(256);

    // fused conversion: (2097152 + 262144 + 131072)/256 = 9728 blocks
    cvt_all<<<dim3(9728), blk, 0, stream>>>(x, Whg, Wout, xb, whgb, woutb);

    // GEMM1: hg[M][2048] = x @ Whg^T  (bf16 out); grid 64x8 = 512
    gemm256<true><<<dim3(512), dim3(512), 0, stream>>>(
        xb, Din, whgb, Din, hgbuf, 2048, Din, 3);

    scan_stage1<<<dim3(Bsz * NCH * Dh / 256), blk, 0, stream>>>(hgbuf, Abuf, hlbuf);
    scan_stage2<<<dim3(Bsz * Dh / 256), blk, 0, stream>>>(Abuf, hlbuf, Hsbuf);
    scan_stage3<<<dim3(Bsz * NCH * Dh / 256), blk, 0, stream>>>(hgbuf, Hsbuf, xb);

    // GEMM2: out[M][1024] = h @ Wout^T  (f32 out); grid 64x4 = 256
    gemm256<false><<<dim3(256), dim3(512), 0, stream>>>(
        xb, Dh, woutb, Din, out, 1024, Dh, 2);
}